// Round 6
// baseline (145.165 us; speedup 1.0000x reference)
//
#include <hip/hip_runtime.h>
#include <hip/hip_fp16.h>

#define N_DET 128
#define N_T   2048
#define NPIX  65536   // 256*256
#define NBATCH 4
#define G 8           // detector rows staged in LDS per block (8 x 16 KB = 128 KB)
#define PT 1024       // pixels per block == threads per block
#define NGB (N_DET / G)

typedef float f4_t __attribute__((ext_vector_type(4)));

// Kernel 1: transpose+pack sino (B, N_DET, N_T) fp32 -> ws (N_DET, N_T) of
// 8-byte records { s_t[b0..b3] } as 4 fp16. ws = 2 MB (L2-resident).
__global__ __launch_bounds__(256) void sino_pack_kernel(
    const float* __restrict__ sino, float2* __restrict__ ws) {
  const int idx = blockIdx.x * blockDim.x + threadIdx.x;  // idx = d*N_T + t
  const __half2 lo = __floats2half2_rn(
      __builtin_nontemporal_load(sino + 0 * N_DET * N_T + idx),
      __builtin_nontemporal_load(sino + 1 * N_DET * N_T + idx));
  const __half2 hi = __floats2half2_rn(
      __builtin_nontemporal_load(sino + 2 * N_DET * N_T + idx),
      __builtin_nontemporal_load(sino + 3 * N_DET * N_T + idx));
  union { struct { __half2 a, b; } h; float2 f; } u;
  u.h.a = lo;
  u.h.b = hi;
  ws[idx] = u.f;
}

// Kernel 2: LDS-gather kernel, occupancy-fixed. Block = 1024 threads
// (16 waves = 4 waves/SIMD on the single resident block - the 128 KB LDS
// allows only 1 block/CU, so the block must carry all the latency hiding).
// Each thread owns one pixel x 8 dets; lut read = one full 64 B line (NT so
// the 64 MB lut stream never evicts the 2 MB L2-resident ws).
// Sino gathers are ds_read_b64 on the LDS pipe (no TA involvement).
__global__ __launch_bounds__(1024, 4) void das_lds_kernel(
    const float* __restrict__ lut, const float2* __restrict__ ws,
    float* __restrict__ out) {
  __shared__ float2 sino_s[G * N_T];  // 128 KB

  const int tid = threadIdx.x;   // 0..1023
  const int tile = blockIdx.x;   // 0..63
  const int g = blockIdx.y;      // 0..15
  const int p = tile * PT + tid;

  // Prefetch this thread's lut line (64 B = 8 dets x (tof, alpha)), NT.
  const f4_t* lp =
      reinterpret_cast<const f4_t*>(lut + ((size_t)p * N_DET + g * G) * 2);
  f4_t l[4];
#pragma unroll
  for (int j = 0; j < 4; ++j) l[j] = __builtin_nontemporal_load(lp + j);

  // Stage 8 det rows: 8192 float4, coalesced from L2-resident ws (8/thread).
  {
    const float4* src = reinterpret_cast<const float4*>(ws + (size_t)g * G * N_T);
    float4* dst = reinterpret_cast<float4*>(sino_s);
#pragma unroll
    for (int i = 0; i < 8192 / 1024; ++i) dst[tid + i * 1024] = src[tid + i * 1024];
  }

  // Apodization for this block's 8 dets (wave-uniform).
  float apd[G];
#pragma unroll
  for (int j = 0; j < G; ++j) {
    apd[j] = 0.5f - 0.5f * cosf(6.28318530717958647692f *
                                ((float)(g * G + j) / (float)(N_DET - 1)));
  }
  __syncthreads();

  float a0 = 0.f, a1 = 0.f, a2 = 0.f, a3 = 0.f;
#pragma unroll
  for (int j = 0; j < G; ++j) {
    const float tof = (j & 1) ? l[j >> 1].z : l[j >> 1].x;
    const float al  = (j & 1) ? l[j >> 1].w : l[j >> 1].y;
    const float kf = floorf(tof);
    const bool valid = (kf >= 0.0f) && (kf < (float)(N_T - 1));
    const float kcl = fminf(fmaxf(kf, 0.0f), (float)(N_T - 2));
    const int k0 = (int)kcl;
    const float w = valid ? apd[j] : 0.0f;

    const float2 r0 = sino_s[j * N_T + k0];      // ds_read_b64: tap t
    const float2 r1 = sino_s[j * N_T + k0 + 1];  // ds_read_b64: tap t+1
    const __half2* h0 = reinterpret_cast<const __half2*>(&r0);
    const __half2* h1 = reinterpret_cast<const __half2*>(&r1);
    const float2 s0a = __half22float2(h0[0]);  // t:   b0,b1
    const float2 s0b = __half22float2(h0[1]);  // t:   b2,b3
    const float2 s1a = __half22float2(h1[0]);  // t+1: b0,b1
    const float2 s1b = __half22float2(h1[1]);  // t+1: b2,b3

    a0 += w * (s0a.x + al * (s1a.x - s0a.x));
    a1 += w * (s0a.y + al * (s1a.y - s0a.y));
    a2 += w * (s0b.x + al * (s1b.x - s0b.x));
    a3 += w * (s0b.y + al * (s1b.y - s0b.y));
  }

  const float nrm = 1.0f / 63.5f;  // sum(apod) == 63.5 analytically
  atomicAdd(out + 0 * NPIX + p, a0 * nrm);
  atomicAdd(out + 1 * NPIX + p, a1 * nrm);
  atomicAdd(out + 2 * NPIX + p, a2 * nrm);
  atomicAdd(out + 3 * NPIX + p, a3 * nrm);
}

// Fallback (no workspace): direct fp32 gather from original layout.
__global__ __launch_bounds__(256) void das_fallback_kernel(
    const float* __restrict__ lut, const float* __restrict__ S,
    float* __restrict__ out) {
  const int lane = threadIdx.x & 63;
  const int p = blockIdx.x * 4 + (threadIdx.x >> 6);

  const float4 lv =
      reinterpret_cast<const float4*>(lut + (size_t)p * 2 * N_DET)[lane];

  float acc0 = 0.f, acc1 = 0.f, acc2 = 0.f, acc3 = 0.f;
  float wsum = 0.f;

#pragma unroll
  for (int j = 0; j < 2; ++j) {
    const int d = 2 * lane + j;
    const float tof = j ? lv.z : lv.x;
    const float a   = j ? lv.w : lv.y;
    const float kf = floorf(tof);
    const bool valid = (kf >= 0.0f) && (kf < (float)(N_T - 1));
    const float kcl = fminf(fmaxf(kf, 0.0f), (float)(N_T - 2));
    const int k0 = (int)kcl;
    const float apd =
        0.5f - 0.5f * cosf(6.28318530717958647692f *
                           (1.0f / (float)(N_DET - 1)) * (float)d);
    wsum += apd;
    const float w = valid ? apd : 0.0f;
    const float om = 1.0f - a;
    const float* row = S + (size_t)d * N_T + k0;
    acc0 += w * (om * row[0 * N_DET * N_T] + a * row[0 * N_DET * N_T + 1]);
    acc1 += w * (om * row[1 * N_DET * N_T] + a * row[1 * N_DET * N_T + 1]);
    acc2 += w * (om * row[2 * N_DET * N_T] + a * row[2 * N_DET * N_T + 1]);
    acc3 += w * (om * row[3 * N_DET * N_T] + a * row[3 * N_DET * N_T + 1]);
  }

#pragma unroll
  for (int off = 32; off > 0; off >>= 1) {
    acc0 += __shfl_xor(acc0, off);
    acc1 += __shfl_xor(acc1, off);
    acc2 += __shfl_xor(acc2, off);
    acc3 += __shfl_xor(acc3, off);
    wsum += __shfl_xor(wsum, off);
  }

  if (lane == 0) {
    const float inv = 1.0f / fmaxf(wsum, 1.17549435e-38f);
    out[0 * NPIX + p] = acc0 * inv;
    out[1 * NPIX + p] = acc1 * inv;
    out[2 * NPIX + p] = acc2 * inv;
    out[3 * NPIX + p] = acc3 * inv;
  }
}

extern "C" void kernel_launch(void* const* d_in, const int* in_sizes, int n_in,
                              void* d_out, int out_size, void* d_ws, size_t ws_size,
                              hipStream_t stream) {
  const float* sino = (const float*)d_in[0];  // (B,1,N_DET,N_T) fp32
  const float* lut  = (const float*)d_in[1];  // (NY,NX,N_DET,2) fp32
  float* out = (float*)d_out;                 // (B,1,NY,NX) fp32

  const size_t need = (size_t)N_DET * N_T * 8;  // 2 MB packed ws
  if (ws_size >= need) {
    hipMemsetAsync(d_out, 0, (size_t)out_size * sizeof(float), stream);
    float2* ws = (float2*)d_ws;
    sino_pack_kernel<<<(N_DET * N_T) / 256, 256, 0, stream>>>(sino, ws);
    dim3 grid(NPIX / PT, NGB);
    das_lds_kernel<<<grid, 1024, 0, stream>>>(lut, ws, out);
  } else {
    das_fallback_kernel<<<NPIX / 4, 256, 0, stream>>>(lut, sino, out);
  }
}

// Round 7
// 122.919 us; speedup vs baseline: 1.1810x; 1.1810x over previous
//
#include <hip/hip_runtime.h>
#include <hip/hip_fp16.h>

#define N_DET 128
#define N_T   2048
#define NPIX  65536   // 256*256
#define NBATCH 4
#define G 4           // detector rows staged in LDS per block (4 x 16 KB = 64 KB -> 2 blocks/CU)
#define PT 1024       // pixels per tile
#define NGB (N_DET / G)   // 32 det groups

typedef float f4_t __attribute__((ext_vector_type(4)));

// Kernel 1: transpose+pack sino (B, N_DET, N_T) fp32 -> ws (N_DET, N_T) of
// 8-byte records { s_t[b0..b3] } as 4 fp16 (ws = 2 MB, L2-resident).
// Also zeroes d_out (1 MB) so the das kernel can accumulate with atomics
// without a separate hipMemsetAsync launch.
__global__ __launch_bounds__(256) void sino_pack_kernel(
    const float* __restrict__ sino, float2* __restrict__ ws,
    float* __restrict__ out) {
  const int idx = blockIdx.x * blockDim.x + threadIdx.x;  // idx = d*N_T + t
  const __half2 lo = __floats2half2_rn(
      __builtin_nontemporal_load(sino + 0 * N_DET * N_T + idx),
      __builtin_nontemporal_load(sino + 1 * N_DET * N_T + idx));
  const __half2 hi = __floats2half2_rn(
      __builtin_nontemporal_load(sino + 2 * N_DET * N_T + idx),
      __builtin_nontemporal_load(sino + 3 * N_DET * N_T + idx));
  union { struct { __half2 a, b; } h; float2 f; } u;
  u.h.a = lo;
  u.h.b = hi;
  ws[idx] = u.f;
  out[idx] = 0.0f;  // idx range == out_size (N_DET*N_T == NPIX*NBATCH == 262144)
}

// Kernel 2: block = (1024-pixel tile) x (4-det group). 64 KB LDS -> 2 blocks
// co-resident per CU, so one block's ds_read/VALU compute overlaps the other
// block's global->LDS staging (the phase-serialization that capped R5/R6).
// 256 threads x 4 pixels/thread keeps the R5 ILP structure.
__global__ __launch_bounds__(256, 2) void das_lds_kernel(
    const float* __restrict__ lut, const float2* __restrict__ ws,
    float* __restrict__ out) {
  __shared__ float2 sino_s[G * N_T];  // 64 KB

  const int tid = threadIdx.x;   // 0..255
  const int tile = blockIdx.x;   // 0..63
  const int g = blockIdx.y;      // 0..31 ; dets 4g..4g+3

  // Prefetch lut for this thread's 4 pixels (32 B each = 2 dwordx4), before
  // staging so the loads are in flight during the LDS writes.
  f4_t l[4][2];
#pragma unroll
  for (int i = 0; i < 4; ++i) {
    const int p = tile * PT + i * 256 + tid;
    const f4_t* lp =
        reinterpret_cast<const f4_t*>(lut + ((size_t)p * N_DET + g * G) * 2);
    l[i][0] = lp[0];
    l[i][1] = lp[1];
  }

  // Stage 4 det rows: 4096 float4 (64 KB), coalesced from L2-resident ws.
  {
    const float4* src = reinterpret_cast<const float4*>(ws + (size_t)g * G * N_T);
    float4* dst = reinterpret_cast<float4*>(sino_s);
#pragma unroll
    for (int i = 0; i < 4096 / 256; ++i) dst[tid + i * 256] = src[tid + i * 256];
  }

  // Apodization for this block's 4 dets (wave-uniform).
  float apd[G];
#pragma unroll
  for (int j = 0; j < G; ++j) {
    apd[j] = 0.5f - 0.5f * cosf(6.28318530717958647692f *
                                ((float)(g * G + j) / (float)(N_DET - 1)));
  }
  __syncthreads();

  const float nrm = 1.0f / 63.5f;  // sum(apod) == 63.5 analytically

#pragma unroll
  for (int i = 0; i < 4; ++i) {
    const int p = tile * PT + i * 256 + tid;
    float a0 = 0.f, a1 = 0.f, a2 = 0.f, a3 = 0.f;
#pragma unroll
    for (int j = 0; j < G; ++j) {
      const float tof = (j & 1) ? l[i][j >> 1].z : l[i][j >> 1].x;
      const float al  = (j & 1) ? l[i][j >> 1].w : l[i][j >> 1].y;
      const float kf = floorf(tof);
      const bool valid = (kf >= 0.0f) && (kf < (float)(N_T - 1));
      const float kcl = fminf(fmaxf(kf, 0.0f), (float)(N_T - 2));
      const int k0 = (int)kcl;
      const float w = valid ? apd[j] : 0.0f;

      const float2 r0 = sino_s[j * N_T + k0];      // taps t, t+1 (ds_read2_b64)
      const float2 r1 = sino_s[j * N_T + k0 + 1];
      const __half2* h0 = reinterpret_cast<const __half2*>(&r0);
      const __half2* h1 = reinterpret_cast<const __half2*>(&r1);
      const float2 s0a = __half22float2(h0[0]);  // t:   b0,b1
      const float2 s0b = __half22float2(h0[1]);  // t:   b2,b3
      const float2 s1a = __half22float2(h1[0]);  // t+1: b0,b1
      const float2 s1b = __half22float2(h1[1]);  // t+1: b2,b3

      a0 += w * (s0a.x + al * (s1a.x - s0a.x));
      a1 += w * (s0a.y + al * (s1a.y - s0a.y));
      a2 += w * (s0b.x + al * (s1b.x - s0b.x));
      a3 += w * (s0b.y + al * (s1b.y - s0b.y));
    }
    atomicAdd(out + 0 * NPIX + p, a0 * nrm);
    atomicAdd(out + 1 * NPIX + p, a1 * nrm);
    atomicAdd(out + 2 * NPIX + p, a2 * nrm);
    atomicAdd(out + 3 * NPIX + p, a3 * nrm);
  }
}

// Fallback (no workspace): direct fp32 gather from original layout.
__global__ __launch_bounds__(256) void das_fallback_kernel(
    const float* __restrict__ lut, const float* __restrict__ S,
    float* __restrict__ out) {
  const int lane = threadIdx.x & 63;
  const int p = blockIdx.x * 4 + (threadIdx.x >> 6);

  const float4 lv =
      reinterpret_cast<const float4*>(lut + (size_t)p * 2 * N_DET)[lane];

  float acc0 = 0.f, acc1 = 0.f, acc2 = 0.f, acc3 = 0.f;
  float wsum = 0.f;

#pragma unroll
  for (int j = 0; j < 2; ++j) {
    const int d = 2 * lane + j;
    const float tof = j ? lv.z : lv.x;
    const float a   = j ? lv.w : lv.y;
    const float kf = floorf(tof);
    const bool valid = (kf >= 0.0f) && (kf < (float)(N_T - 1));
    const float kcl = fminf(fmaxf(kf, 0.0f), (float)(N_T - 2));
    const int k0 = (int)kcl;
    const float apd =
        0.5f - 0.5f * cosf(6.28318530717958647692f *
                           (1.0f / (float)(N_DET - 1)) * (float)d);
    wsum += apd;
    const float w = valid ? apd : 0.0f;
    const float om = 1.0f - a;
    const float* row = S + (size_t)d * N_T + k0;
    acc0 += w * (om * row[0 * N_DET * N_T] + a * row[0 * N_DET * N_T + 1]);
    acc1 += w * (om * row[1 * N_DET * N_T] + a * row[1 * N_DET * N_T + 1]);
    acc2 += w * (om * row[2 * N_DET * N_T] + a * row[2 * N_DET * N_T + 1]);
    acc3 += w * (om * row[3 * N_DET * N_T] + a * row[3 * N_DET * N_T + 1]);
  }

#pragma unroll
  for (int off = 32; off > 0; off >>= 1) {
    acc0 += __shfl_xor(acc0, off);
    acc1 += __shfl_xor(acc1, off);
    acc2 += __shfl_xor(acc2, off);
    acc3 += __shfl_xor(acc3, off);
    wsum += __shfl_xor(wsum, off);
  }

  if (lane == 0) {
    const float inv = 1.0f / fmaxf(wsum, 1.17549435e-38f);
    out[0 * NPIX + p] = acc0 * inv;
    out[1 * NPIX + p] = acc1 * inv;
    out[2 * NPIX + p] = acc2 * inv;
    out[3 * NPIX + p] = acc3 * inv;
  }
}

extern "C" void kernel_launch(void* const* d_in, const int* in_sizes, int n_in,
                              void* d_out, int out_size, void* d_ws, size_t ws_size,
                              hipStream_t stream) {
  const float* sino = (const float*)d_in[0];  // (B,1,N_DET,N_T) fp32
  const float* lut  = (const float*)d_in[1];  // (NY,NX,N_DET,2) fp32
  float* out = (float*)d_out;                 // (B,1,NY,NX) fp32

  const size_t need = (size_t)N_DET * N_T * 8;  // 2 MB packed ws
  if (ws_size >= need) {
    float2* ws = (float2*)d_ws;
    sino_pack_kernel<<<(N_DET * N_T) / 256, 256, 0, stream>>>(sino, ws, out);
    dim3 grid(NPIX / PT, NGB);
    das_lds_kernel<<<grid, 256, 0, stream>>>(lut, ws, out);
  } else {
    das_fallback_kernel<<<NPIX / 4, 256, 0, stream>>>(lut, sino, out);
  }
}